// Round 2
// baseline (782.467 us; speedup 1.0000x reference)
//
#include <hip/hip_runtime.h>
#include <hip/hip_bf16.h>

// ---------------------------------------------------------------------------
// GIN forward (all I/O fp32):
//   2x GINConv(128->128->128, eps=0) + ReLU, L2 row-normalize,
//   per-node MLP 128->32->32->32, per-graph Gram (32x32 -> 1024),
//   per-graph MLP 1024->32->32->2.
// Internals: node features stored bf16 (gather traffic / MFMA), fp32 accum.
// ---------------------------------------------------------------------------

#define NN 131072      // nodes
#define NE 2097152     // edges
#define NG 512         // graphs
#define GSZ 256        // nodes per graph

typedef unsigned short u16;
typedef unsigned int u32;
typedef __attribute__((ext_vector_type(8))) short short8;   // 8 x bf16
typedef __attribute__((ext_vector_type(4))) float f32x4;

__device__ __forceinline__ float bf2f(u16 u) {
    union { u32 i; float f; } x; x.i = ((u32)u) << 16; return x.f;
}
__device__ __forceinline__ u16 f2bf(float f) {
    union { u32 i; float f; } x; x.f = f;
    u32 r = x.i + 0x7fffu + ((x.i >> 16) & 1u);   // RNE
    return (u16)(r >> 16);
}

// ---------------- cast x: fp32 -> bf16 ----------------
__global__ __launch_bounds__(256) void cast_x(const float* __restrict__ xf,
                                              u16* __restrict__ xb) {
    int i = blockIdx.x * 256 + threadIdx.x;       // 8 floats per thread
    const float4* src = (const float4*)xf;
    float4 a = src[2 * i], b = src[2 * i + 1];
    uint4 o;
    o.x = (u32)f2bf(a.x) | ((u32)f2bf(a.y) << 16);
    o.y = (u32)f2bf(a.z) | ((u32)f2bf(a.w) << 16);
    o.z = (u32)f2bf(b.x) | ((u32)f2bf(b.y) << 16);
    o.w = (u32)f2bf(b.z) | ((u32)f2bf(b.w) << 16);
    ((uint4*)xb)[i] = o;
}

// ---------------- CSR build ----------------
__global__ __launch_bounds__(256) void edge_count(const int* ei, int* cnt) {
    int e = blockIdx.x * 256 + threadIdx.x;
    atomicAdd(&cnt[ei[NE + e]], 1);
}

__global__ __launch_bounds__(256) void scan1(const int* cnt, int* incl, int* sums) {
    __shared__ int tmp[256];
    int t = threadIdx.x, g = blockIdx.x * 256 + t;
    tmp[t] = cnt[g]; __syncthreads();
    for (int o = 1; o < 256; o <<= 1) {
        int u = (t >= o) ? tmp[t - o] : 0;
        __syncthreads();
        tmp[t] += u;
        __syncthreads();
    }
    incl[g] = tmp[t];
    if (t == 255) sums[blockIdx.x] = tmp[t];
}

__global__ __launch_bounds__(512) void scan2(int* sums) {
    __shared__ int tmp[512];
    int t = threadIdx.x;
    tmp[t] = sums[t]; __syncthreads();
    for (int o = 1; o < 512; o <<= 1) {
        int u = (t >= o) ? tmp[t - o] : 0;
        __syncthreads();
        tmp[t] += u;
        __syncthreads();
    }
    sums[t] = tmp[t];
}

__global__ __launch_bounds__(256) void scan3(const int* cnt, const int* incl, const int* sumsI,
                                             int* ptr, int* nxt) {
    int g = blockIdx.x * 256 + threadIdx.x;
    int base = blockIdx.x ? sumsI[blockIdx.x - 1] : 0;
    int ex = base + incl[g] - cnt[g];
    ptr[g] = ex;
    nxt[g] = ex;
    if (g == 0) ptr[NN] = sumsI[511];
}

__global__ __launch_bounds__(256) void edge_scatter(const int* ei, int* nxt, int* esrc) {
    int e = blockIdx.x * 256 + threadIdx.x;
    int d = ei[NE + e];
    int p = atomicAdd(&nxt[d], 1);
    esrc[p] = ei[e];
}

// ---------------- aggregation: T[i] = X[i] + sum_{j->i} X[j] (bf16 rows) ----------------
__global__ __launch_bounds__(256) void aggregate(const u16* __restrict__ X,
                                                 const int* __restrict__ ptr,
                                                 const int* __restrict__ esrc,
                                                 u16* __restrict__ T) {
    int wave = threadIdx.x >> 6, lane = threadIdx.x & 63;
    int node = blockIdx.x * 4 + wave;
    const u32* Xu = (const u32*)X;
    u32 v = Xu[(size_t)node * 64 + lane];
    float a0 = bf2f((u16)v), a1 = bf2f((u16)(v >> 16));
    int p0 = ptr[node], p1 = ptr[node + 1];
    int p = p0;
    for (; p + 4 <= p1; p += 4) {            // unroll: 4 independent gathers in flight
        int s0 = esrc[p], s1 = esrc[p + 1], s2 = esrc[p + 2], s3 = esrc[p + 3];
        u32 w0 = Xu[(size_t)s0 * 64 + lane];
        u32 w1 = Xu[(size_t)s1 * 64 + lane];
        u32 w2 = Xu[(size_t)s2 * 64 + lane];
        u32 w3 = Xu[(size_t)s3 * 64 + lane];
        a0 += bf2f((u16)w0) + bf2f((u16)w1) + bf2f((u16)w2) + bf2f((u16)w3);
        a1 += bf2f((u16)(w0 >> 16)) + bf2f((u16)(w1 >> 16)) +
              bf2f((u16)(w2 >> 16)) + bf2f((u16)(w3 >> 16));
    }
    for (; p < p1; ++p) {
        int s = esrc[p];
        u32 w = Xu[(size_t)s * 64 + lane];
        a0 += bf2f((u16)w);
        a1 += bf2f((u16)(w >> 16));
    }
    ((u32*)T)[(size_t)node * 64 + lane] = (u32)f2bf(a0) | ((u32)f2bf(a1) << 16);
}

// ---------------- weight transpose + cast: Wt[n][k] = (bf16)W[k][n] ----------------
__global__ __launch_bounds__(256) void transpose_w(const float* a, const float* b,
                                                   const float* c, const float* d, u16* Wt) {
    const float* w = (blockIdx.x == 0) ? a : (blockIdx.x == 1) ? b : (blockIdx.x == 2) ? c : d;
    u16* o = Wt + blockIdx.x * 16384;
    for (int i = 0; i < 64; ++i) {
        int idx = threadIdx.x + i * 256;
        o[(idx & 127) * 128 + (idx >> 7)] = f2bf(w[idx]);
    }
}

// ---------------- GEMM: C = relu(A @ W + b) via MFMA bf16 ----------------
__global__ __launch_bounds__(256) void gemm_relu(const u16* __restrict__ A,
                                                 const u16* __restrict__ Wt,
                                                 const float* __restrict__ bias,
                                                 u16* __restrict__ C) {
    __shared__ u16 As[64][136];
    __shared__ u16 Ws[128][136];
    int tid = threadIdx.x;
    size_t rowBase = (size_t)blockIdx.x * 64;

    for (int i = 0; i < 4; ++i) {
        int c = tid + i * 256;
        int r = c >> 4, co = (c & 15) << 3;
        uint4 v = *(const uint4*)(A + (rowBase + r) * 128 + co);
        *(uint4*)&As[r][co] = v;
    }
    for (int i = 0; i < 8; ++i) {
        int c = tid + i * 256;
        int r = c >> 4, co = (c & 15) << 3;
        uint4 v = *(const uint4*)(Wt + r * 128 + co);
        *(uint4*)&Ws[r][co] = v;
    }
    __syncthreads();

    int lane = tid & 63, wave = tid >> 6;
    int quad = lane >> 4, l16 = lane & 15;

    f32x4 acc[8];
#pragma unroll
    for (int t = 0; t < 8; ++t) acc[t] = (f32x4){0.f, 0.f, 0.f, 0.f};

#pragma unroll
    for (int c = 0; c < 4; ++c) {
        short8 a = *(const short8*)&As[wave * 16 + l16][c * 32 + quad * 8];
#pragma unroll
        for (int t = 0; t < 8; ++t) {
            short8 b = *(const short8*)&Ws[t * 16 + l16][c * 32 + quad * 8];
            acc[t] = __builtin_amdgcn_mfma_f32_16x16x32_bf16(a, b, acc[t], 0, 0, 0);
        }
    }

#pragma unroll
    for (int t = 0; t < 8; ++t) {
        int col = t * 16 + l16;
        float bv = bias[col];
#pragma unroll
        for (int r = 0; r < 4; ++r) {
            int row = wave * 16 + quad * 4 + r;
            float v = fmaxf(acc[t][r] + bv, 0.f);
            C[(rowBase + row) * 128 + col] = f2bf(v);
        }
    }
}

// ---------------- normalize + per-node MLP (128->32->32->32), fp32 weights ----------------
__global__ __launch_bounds__(256) void norm_mlp(const u16* __restrict__ X,
                                                const float* Ws1, const float* bs1,
                                                const float* Ws2, const float* bs2,
                                                const float* Ws3, const float* bs3,
                                                float* __restrict__ S) {
    __shared__ float W1s[128 * 32];
    __shared__ float W2s[32 * 32];
    __shared__ float W3s[32 * 32];
    __shared__ float b1s[32], b2s[32], b3s[32];
    __shared__ float hbuf[4][128];
    __shared__ float sbuf[4][32];
    int t = threadIdx.x;
    for (int i = 0; i < 16; ++i) W1s[t + i * 256] = Ws1[t + i * 256];
    for (int i = 0; i < 4; ++i) { W2s[t + i * 256] = Ws2[t + i * 256]; W3s[t + i * 256] = Ws3[t + i * 256]; }
    if (t < 32) { b1s[t] = bs1[t]; b2s[t] = bs2[t]; b3s[t] = bs3[t]; }
    __syncthreads();

    int wave = t >> 6, lane = t & 63;
    int node = blockIdx.x * 4 + wave;
    u32 v = ((const u32*)X)[(size_t)node * 64 + lane];
    float f0 = bf2f((u16)v), f1 = bf2f((u16)(v >> 16));
    float ss = f0 * f0 + f1 * f1;
    for (int o = 1; o < 64; o <<= 1) ss += __shfl_xor(ss, o, 64);
    float inv = 1.0f / fmaxf(sqrtf(ss), 1e-12f);
    hbuf[wave][2 * lane] = f0 * inv;
    hbuf[wave][2 * lane + 1] = f1 * inv;
    __syncthreads();

    int j = lane & 31, half = lane >> 5;
    float p = 0.f;
    for (int i = 0; i < 64; ++i) { int k = half * 64 + i; p += hbuf[wave][k] * W1s[k * 32 + j]; }
    p += __shfl_xor(p, 32, 64);
    float s1 = fmaxf(p + b1s[j], 0.f);
    if (!half) sbuf[wave][j] = s1;
    __syncthreads();

    p = 0.f;
    for (int i = 0; i < 16; ++i) { int k = half * 16 + i; p += sbuf[wave][k] * W2s[k * 32 + j]; }
    p += __shfl_xor(p, 32, 64);
    float s2 = fmaxf(p + b2s[j], 0.f);
    __syncthreads();
    if (!half) sbuf[wave][j] = s2;
    __syncthreads();

    p = 0.f;
    for (int i = 0; i < 16; ++i) { int k = half * 16 + i; p += sbuf[wave][k] * W3s[k * 32 + j]; }
    p += __shfl_xor(p, 32, 64);
    float s3 = fmaxf(p + b3s[j], 0.f);
    if (!half) S[(size_t)node * 32 + j] = s3;
}

// ---------------- per-graph Gram: out[g][f][e] = sum_n S[g,n,f]*S[g,n,e] ----------------
__global__ __launch_bounds__(256) void gram(const float* __restrict__ S,
                                            float* __restrict__ out) {
    __shared__ float Sg[256 * 32];
    int t = threadIdx.x, g = blockIdx.x;
    const float4* src = (const float4*)(S + (size_t)g * 8192);
    float4* dst = (float4*)Sg;
    for (int i = 0; i < 8; ++i) dst[t + i * 256] = src[t + i * 256];
    __syncthreads();

    int f = t >> 3, e0 = (t & 7) << 2;
    float4 a = {0.f, 0.f, 0.f, 0.f};
    for (int n = 0; n < 256; ++n) {
        float sf = Sg[n * 32 + f];
        float4 se = *(const float4*)&Sg[n * 32 + e0];
        a.x += sf * se.x; a.y += sf * se.y; a.z += sf * se.z; a.w += sf * se.w;
    }
    *(float4*)(out + (size_t)g * 1024 + f * 32 + e0) = a;
}

// ---------------- per-graph MLP: 1024->32->32->2 (fp32) ----------------
__global__ __launch_bounds__(256) void graph_mlp(const float* __restrict__ HH,
                                                 const float* Wm1, const float* bm1,
                                                 const float* Wm2, const float* bm2,
                                                 const float* Wm3, const float* bm3,
                                                 float* __restrict__ out) {
    __shared__ float hh[1024];
    __shared__ float red[256];
    __shared__ float o1[32];
    __shared__ float o2[32];
    int t = threadIdx.x, g = blockIdx.x;
    ((float4*)hh)[t] = ((const float4*)(HH + (size_t)g * 1024))[t];
    __syncthreads();

    int j = t & 31, part = t >> 5;
    float p = 0.f;
    for (int i = 0; i < 128; ++i) { int k = part * 128 + i; p += hh[k] * Wm1[k * 32 + j]; }
    red[t] = p;
    __syncthreads();
    if (t < 32) {
        float s = 0.f;
        for (int q = 0; q < 8; ++q) s += red[q * 32 + t];
        o1[t] = fmaxf(s + bm1[t], 0.f);
    }
    __syncthreads();
    if (t < 32) {
        float s = 0.f;
        for (int k = 0; k < 32; ++k) s += o1[k] * Wm2[k * 32 + t];
        o2[t] = fmaxf(s + bm2[t], 0.f);
    }
    __syncthreads();
    if (t < 2) {
        float s = 0.f;
        for (int k = 0; k < 32; ++k) s += o2[k] * Wm3[k * 2 + t];
        out[524288 + g * 2 + t] = fmaxf(s + bm3[t], 0.f);
    }
}

// ---------------------------------------------------------------------------
extern "C" void kernel_launch(void* const* d_in, const int* in_sizes, int n_in,
                              void* d_out, int out_size, void* d_ws, size_t ws_size,
                              hipStream_t stream) {
    const float* x   = (const float*)d_in[0];
    const int*   ei  = (const int*)d_in[1];
    const float* W1a = (const float*)d_in[2];  const float* b1a = (const float*)d_in[3];
    const float* W2a = (const float*)d_in[4];  const float* b2a = (const float*)d_in[5];
    const float* W1b = (const float*)d_in[6];  const float* b1b = (const float*)d_in[7];
    const float* W2b = (const float*)d_in[8];  const float* b2b = (const float*)d_in[9];
    const float* Ws1 = (const float*)d_in[10]; const float* bs1 = (const float*)d_in[11];
    const float* Ws2 = (const float*)d_in[12]; const float* bs2 = (const float*)d_in[13];
    const float* Ws3 = (const float*)d_in[14]; const float* bs3 = (const float*)d_in[15];
    const float* Wm1 = (const float*)d_in[16]; const float* bm1 = (const float*)d_in[17];
    const float* Wm2 = (const float*)d_in[18]; const float* bm2 = (const float*)d_in[19];
    const float* Wm3 = (const float*)d_in[20]; const float* bm3 = (const float*)d_in[21];
    float* out = (float*)d_out;

    char* ws = (char*)d_ws;
    size_t off = 0;
    auto alloc = [&](size_t bytes) { size_t r = off; off = (off + bytes + 255) & ~(size_t)255; return r; };
    int*  cnt   = (int*)(ws + alloc((size_t)NN * 4));
    int*  incl  = (int*)(ws + alloc((size_t)NN * 4));
    int*  sums  = (int*)(ws + alloc(512 * 4));
    int*  ptr   = (int*)(ws + alloc((size_t)(NN + 1) * 4));
    int*  nxt   = (int*)(ws + alloc((size_t)NN * 4));
    int*  esrc  = (int*)(ws + alloc((size_t)NE * 4));
    u16*  Wt    = (u16*)(ws + alloc(4 * 16384 * 2));
    u16*  X0    = (u16*)(ws + alloc((size_t)NN * 128 * 2));   // xb / hA / hB
    u16*  B1    = (u16*)(ws + alloc((size_t)NN * 128 * 2));
    u16*  B2    = (u16*)(ws + alloc((size_t)NN * 128 * 2));
    float* S    = (float*)B1;                                  // alias: B1 dead after last gemm
    (void)ws_size; (void)n_in; (void)in_sizes; (void)out_size;

    // CSR build
    hipMemsetAsync(cnt, 0, (size_t)NN * 4, stream);
    edge_count<<<NE / 256, 256, 0, stream>>>(ei, cnt);
    scan1<<<NN / 256, 256, 0, stream>>>(cnt, incl, sums);
    scan2<<<1, 512, 0, stream>>>(sums);
    scan3<<<NN / 256, 256, 0, stream>>>(cnt, incl, sums, ptr, nxt);
    edge_scatter<<<NE / 256, 256, 0, stream>>>(ei, nxt, esrc);

    // casts
    cast_x<<<NN * 128 / (256 * 8), 256, 0, stream>>>(x, X0);
    transpose_w<<<4, 256, 0, stream>>>(W1a, W2a, W1b, W2b, Wt);

    // layer A
    aggregate<<<NN / 4, 256, 0, stream>>>(X0, ptr, esrc, B1);
    gemm_relu<<<NN / 64, 256, 0, stream>>>(B1, Wt + 0 * 16384, b1a, B2);
    gemm_relu<<<NN / 64, 256, 0, stream>>>(B2, Wt + 1 * 16384, b2a, X0);   // hA
    // layer B
    aggregate<<<NN / 4, 256, 0, stream>>>(X0, ptr, esrc, B1);
    gemm_relu<<<NN / 64, 256, 0, stream>>>(B1, Wt + 2 * 16384, b1b, B2);
    gemm_relu<<<NN / 64, 256, 0, stream>>>(B2, Wt + 3 * 16384, b2b, X0);   // hB

    // normalize + per-node MLP  (S aliases B1)
    norm_mlp<<<NN / 4, 256, 0, stream>>>(X0, Ws1, bs1, Ws2, bs2, Ws3, bs3, S);
    // per-graph Gram -> out[0:524288], then graph MLP -> out[524288:]
    gram<<<NG, 256, 0, stream>>>(S, out);
    graph_mlp<<<NG, 256, 0, stream>>>(out, Wm1, bm1, Wm2, bm2, Wm3, bm3, out);
}